// Round 1
// baseline (133.116 us; speedup 1.0000x reference)
//
#include <hip/hip_runtime.h>

// RegionLayer (YOLOv2 region loss) on gfx950.
// B=16, A=5, nC=20, nH=nW=64, MAX_BOXES=50. Output: scalar loss (float32).

#define NCLS 20
#define NA 5
#define NB 16
#define NH 64
#define NW 64
#define MAXB 50
#define THRESH 0.6f
#define OBJECT_SCALE 5.0f
#define CELLS_PER_B (NA * NH * NW)   // 20480
#define NCELLS (NB * CELLS_PER_B)    // 327680

// Phase A: parse targets. One thread per batch, sequential over boxes so the
// "last box wins" overwrite order of the reference scan is preserved via the
// compact box list (phase B takes the LAST matching code).
// boxrec layout per box: [gx, gy, gw, gh, cls, code(int bits)] — 6 floats.
__global__ void build_targets_kernel(const float* __restrict__ target,
                                     const float* __restrict__ anchors,
                                     float* __restrict__ boxrec,  // [NB*MAXB*6]
                                     int* __restrict__ nvalid,    // [NB]
                                     float* __restrict__ out) {
    if (threadIdx.x == 0) out[0] = 0.0f;  // d_out is poisoned 0xAA each call
    int b = threadIdx.x;
    if (b >= NB) return;
    float aw[NA], ah[NA];
#pragma unroll
    for (int a = 0; a < NA; ++a) { aw[a] = anchors[2 * a]; ah[a] = anchors[2 * a + 1]; }
    int cnt = 0;
    for (int t = 0; t < MAXB; ++t) {
        const float* tb = target + (b * MAXB + t) * 5;
        float cls = tb[0];
        float x = tb[1];
        if (x == 0.0f) break;  // cumprod(valid) semantics: first zero ends the list
        float gx = x * NW;
        float gy = tb[2] * NH;
        float gw = tb[3] * NW;
        float gh = tb[4] * NH;
        int gi = (int)gx; gi = max(0, min(NW - 1, gi));
        int gj = (int)gy; gj = max(0, min(NH - 1, gj));
        // argmax over anchors of IoU((gw,gh),(aw,ah)) centered at origin; first max wins
        int best = 0; float bestv = -1.0f;
#pragma unroll
        for (int a = 0; a < NA; ++a) {
            float inter = fminf(gw, aw[a]) * fminf(gh, ah[a]);
            float uni = gw * gh + aw[a] * ah[a] - inter;
            float r = inter / uni;
            if (r > bestv) { bestv = r; best = a; }
        }
        float* rec = boxrec + (b * MAXB + cnt) * 6;
        rec[0] = gx; rec[1] = gy; rec[2] = gw; rec[3] = gh; rec[4] = cls;
        rec[5] = __int_as_float((best << 12) | (gj << 6) | gi);
        ++cnt;
    }
    nvalid[b] = cnt;
}

// Phase B: one thread per cell (b,a,j,i). Block = 256 consecutive cells in a
// single (b,a). Batch's box list staged in LDS. Dense read: channels 0..4
// only; class logits fetched only at owner cells.
__global__ __launch_bounds__(256) void region_loss_kernel(
    const float* __restrict__ output,
    const float* __restrict__ boxrec,
    const int* __restrict__ nvalid,
    const float* __restrict__ anchors,
    float* __restrict__ out) {
    int cell = blockIdx.x * 256 + threadIdx.x;
    int b = cell / CELLS_PER_B;
    int rem = cell - b * CELLS_PER_B;
    int a = rem >> 12;           // / (NH*NW)
    int p = rem & 4095;          // j*NW + i
    int i = p & 63;
    int j = p >> 6;

    __shared__ float4 sbox[MAXB];
    __shared__ int scode[MAXB];
    __shared__ float scls[MAXB];

    int nv = nvalid[b];
    if ((int)threadIdx.x < nv) {
        const float* rec = boxrec + (b * MAXB + threadIdx.x) * 6;
        sbox[threadIdx.x] = make_float4(rec[0], rec[1], rec[2], rec[3]);
        scls[threadIdx.x] = rec[4];
        scode[threadIdx.x] = __float_as_int(rec[5]);
    }
    __syncthreads();

    const float* base = output + ((size_t)b * 125 + (size_t)a * 25) * 4096 + p;
    float xo = base[0];
    float yo = base[4096];
    float wo = base[2 * 4096];
    float ho = base[3 * 4096];
    float co = base[4 * 4096];

    float sigx = 1.0f / (1.0f + __expf(-xo));
    float sigy = 1.0f / (1.0f + __expf(-yo));
    float conf = 1.0f / (1.0f + __expf(-co));

    float aw = anchors[2 * a], ah = anchors[2 * a + 1];
    float pw = __expf(wo) * aw;
    float ph = __expf(ho) * ah;
    float px = sigx + (float)i;
    float py = sigy + (float)j;
    float phw = 0.5f * pw, phh = 0.5f * ph;
    float area_p = pw * ph;

    int mycode = (a << 12) | p;
    int own = -1;
    float maxiou = 0.0f;
    for (int t = 0; t < nv; ++t) {
        float4 g = sbox[t];
        float l = fmaxf(px - phw, g.x - 0.5f * g.z);
        float r = fminf(px + phw, g.x + 0.5f * g.z);
        float tt = fmaxf(py - phh, g.y - 0.5f * g.w);
        float bb = fminf(py + phh, g.y + 0.5f * g.w);
        float inter = fmaxf(r - l, 0.0f) * fmaxf(bb - tt, 0.0f);
        float uni = area_p + g.z * g.w - inter;
        maxiou = fmaxf(maxiou, inter / uni);
        if (scode[t] == mycode) own = t;  // last match wins (scan overwrite order)
    }

    float conf_mask = (maxiou > THRESH) ? 0.0f : 1.0f;  // NOOBJECT_SCALE = 1
    float tx = 0.5f, ty = 0.5f, tw = 0.0f, th = 0.0f, tconf = 0.0f;
    float loss = 0.0f;

    if (own >= 0) {
        float4 g = sbox[own];
        tx = g.x - (float)i;          // gi == i for the owner cell
        ty = g.y - (float)j;
        tw = __logf(g.z / aw);        // best_n == a for the owner cell
        th = __logf(g.w / ah);
        // tconf = IoU(gt, pb[this cell])
        float l = fmaxf(px - phw, g.x - 0.5f * g.z);
        float r = fminf(px + phw, g.x + 0.5f * g.z);
        float tt = fmaxf(py - phh, g.y - 0.5f * g.w);
        float bb = fminf(py + phh, g.y + 0.5f * g.w);
        float inter = fmaxf(r - l, 0.0f) * fmaxf(bb - tt, 0.0f);
        float uni = area_p + g.z * g.w - inter;
        tconf = inter / uni;
        conf_mask = OBJECT_SCALE;

        // class cross-entropy at this cell (CLASS_SCALE = 1)
        int tcls = (int)scls[own];
        float logits[NCLS];
        float m = -1e30f;
#pragma unroll
        for (int c = 0; c < NCLS; ++c) {
            logits[c] = base[(5 + c) * 4096];
            m = fmaxf(m, logits[c]);
        }
        float s = 0.0f;
#pragma unroll
        for (int c = 0; c < NCLS; ++c) s += __expf(logits[c] - m);
        float lse = m + __logf(s);
        loss += lse - logits[tcls];
    }

    float dx = sigx - tx, dy = sigy - ty, dw = wo - tw, dh = ho - th;
    loss += 0.5f * (dx * dx + dy * dy + dw * dw + dh * dh);  // COORD_SCALE=1, cm==1
    float dc = conf - tconf;
    loss += 0.5f * conf_mask * dc * dc;

    // reduce: shfl within wave64, then LDS across 4 waves, one atomic per block
#pragma unroll
    for (int off = 32; off > 0; off >>= 1) loss += __shfl_down(loss, off, 64);
    __shared__ float wsum[4];
    if ((threadIdx.x & 63) == 0) wsum[threadIdx.x >> 6] = loss;
    __syncthreads();
    if (threadIdx.x == 0) atomicAdd(out, wsum[0] + wsum[1] + wsum[2] + wsum[3]);
}

extern "C" void kernel_launch(void* const* d_in, const int* in_sizes, int n_in,
                              void* d_out, int out_size, void* d_ws, size_t ws_size,
                              hipStream_t stream) {
    const float* output  = (const float*)d_in[0];
    const float* target  = (const float*)d_in[1];
    const float* anchors = (const float*)d_in[2];
    float* out = (float*)d_out;

    float* boxrec = (float*)d_ws;                             // NB*MAXB*6 floats = 19.2 KB
    int* nvalid = (int*)((char*)d_ws + NB * MAXB * 6 * sizeof(float));

    build_targets_kernel<<<1, 64, 0, stream>>>(target, anchors, boxrec, nvalid, out);
    region_loss_kernel<<<NCELLS / 256, 256, 0, stream>>>(output, boxrec, nvalid, anchors, out);
}

// Round 2
// 87.855 us; speedup vs baseline: 1.5152x; 1.5152x over previous
//
#include <hip/hip_runtime.h>

// RegionLayer (YOLOv2 region loss) on gfx950 — fused single-pass version.
// B=16, A=5, nC=20, nH=nW=64, MAX_BOXES=50. Output: scalar loss (float32).
//
// Each block handles 256 consecutive cells of one (b,a) plane and redundantly
// parses its batch's 50-box target list (16 KB total, L2/L3-resident) in wave 0
// — removes the serial phase-A kernel and the cross-kernel dependency.
// conf_mask test is division-free: iou>0.6 <=> inter > 0.375*(area_p+area_g).
// Deterministic reduction: per-block partial -> d_ws, tiny reduce kernel
// overwrites d_out (no zero-init needed despite 0xAA poison).

#define NCLS 20
#define NA 5
#define NB 16
#define NH 64
#define NW 64
#define MAXB 50
#define OBJECT_SCALE 5.0f
#define CELLS_PER_B (NA * NH * NW)   // 20480
#define NCELLS (NB * CELLS_PER_B)    // 327680
#define NBLOCKS (NCELLS / 256)       // 1280

__global__ __launch_bounds__(256) void region_loss_kernel(
    const float* __restrict__ output,
    const float* __restrict__ target,
    const float* __restrict__ anchors,
    float* __restrict__ part) {
    const int cell = blockIdx.x * 256 + threadIdx.x;
    const int b = cell / CELLS_PER_B;
    const int rem = cell - b * CELLS_PER_B;
    const int a = rem >> 12;           // / (NH*NW)
    const int p = rem & 4095;          // j*NW + i
    const int i = p & 63;
    const int j = p >> 6;

    __shared__ float4 scrn[MAXB];      // (x0, x1, y0, y1) box corners
    __shared__ float4 sctr[MAXB];      // (gx, gy, gw, gh) center form
    __shared__ float scg[MAXB];        // 0.375 * gw * gh
    __shared__ int scode[MAXB];        // (best_n<<12)|(gj<<6)|gi
    __shared__ float scls[MAXB];
    __shared__ int snv;

    // ---- wave 0: parallel target parse for batch b ----
    if (threadIdx.x < 64) {
        const int t = threadIdx.x;
        float cls = 0.f, x = 0.f, y = 0.f, w = 0.f, h = 0.f;
        if (t < MAXB) {
            const float* tb = target + (b * MAXB + t) * 5;
            cls = tb[0]; x = tb[1]; y = tb[2]; w = tb[3]; h = tb[4];
        }
        // validity is a prefix: cumprod(x != 0)
        unsigned long long m = __ballot(x != 0.0f);
        if (t == 0) snv = (int)(__ffsll((long long)~m) - 1);  // trailing-ones count, <= 50
        if (t < MAXB) {
            float gx = x * NW, gy = y * NH, gw = w * NW, gh = h * NH;
            int gi = max(0, min(NW - 1, (int)gx));
            int gj = max(0, min(NH - 1, (int)gy));
            int best = 0; float bestv = -1.0f;
#pragma unroll
            for (int aa = 0; aa < NA; ++aa) {
                float aw = anchors[2 * aa], ah = anchors[2 * aa + 1];
                float inter = fminf(gw, aw) * fminf(gh, ah);
                float uni = gw * gh + aw * ah - inter;
                float r = inter / uni;
                if (r > bestv) { bestv = r; best = aa; }
            }
            scrn[t] = make_float4(gx - 0.5f * gw, gx + 0.5f * gw,
                                  gy - 0.5f * gh, gy + 0.5f * gh);
            sctr[t] = make_float4(gx, gy, gw, gh);
            scg[t] = 0.375f * gw * gh;
            scode[t] = (best << 12) | (gj << 6) | gi;
            scls[t] = cls;
        }
    }
    __syncthreads();
    const int nv = snv;

    // ---- per-cell prediction ----
    const float* base = output + ((size_t)b * 125 + (size_t)a * 25) * 4096 + p;
    float xo = base[0];
    float yo = base[4096];
    float wo = base[2 * 4096];
    float ho = base[3 * 4096];
    float co = base[4 * 4096];

    float sigx = 1.0f / (1.0f + __expf(-xo));
    float sigy = 1.0f / (1.0f + __expf(-yo));
    float conf = 1.0f / (1.0f + __expf(-co));

    float aw = anchors[2 * a], ah = anchors[2 * a + 1];
    float pw = __expf(wo) * aw;
    float ph = __expf(ho) * ah;
    float px = sigx + (float)i;
    float py = sigy + (float)j;
    float phw = 0.5f * pw, phh = 0.5f * ph;
    float pxl = px - phw, pxr = px + phw;
    float pyt = py - phh, pyb = py + phh;
    float area_p = pw * ph;
    float cp = 0.375f * area_p;        // THRESH/(1+THRESH) * area_p

    const int mycode = (a << 12) | p;
    int own = -1;
    bool over = false;                 // any IoU(pred, gt) > 0.6
    for (int t = 0; t < nv; ++t) {
        float4 g = scrn[t];            // LDS broadcast, conflict-free
        float l = fmaxf(pxl, g.x);
        float r = fminf(pxr, g.y);
        float tt = fmaxf(pyt, g.z);
        float bb = fminf(pyb, g.w);
        float inter = fmaxf(r - l, 0.0f) * fmaxf(bb - tt, 0.0f);
        over = over || (inter > cp + scg[t]);   // div-free: iou>0.6
        own = (scode[t] == mycode) ? t : own;   // last match wins (scan order)
    }

    float conf_mask = over ? 0.0f : 1.0f;       // NOOBJECT_SCALE = 1
    float tconf = 0.0f;
    float loss = 0.0f;
    float tx = 0.5f, ty = 0.5f, tw = 0.0f, th = 0.0f;

    if (own >= 0) {
        float4 g = sctr[own];
        tx = g.x - (float)i;           // gi == i at the owner cell
        ty = g.y - (float)j;
        tw = __logf(g.z / aw);         // best_n == a at the owner cell
        th = __logf(g.w / ah);
        float4 c = scrn[own];
        float l = fmaxf(pxl, c.x);
        float r = fminf(pxr, c.y);
        float tt = fmaxf(pyt, c.z);
        float bb = fminf(pyb, c.w);
        float inter = fmaxf(r - l, 0.0f) * fmaxf(bb - tt, 0.0f);
        float uni = area_p + g.z * g.w - inter;
        tconf = inter / uni;
        conf_mask = OBJECT_SCALE;

        // class cross-entropy at this cell (CLASS_SCALE = 1)
        int tcls = (int)scls[own];
        float logits[NCLS];
        float mx = -1e30f;
#pragma unroll
        for (int c2 = 0; c2 < NCLS; ++c2) {
            logits[c2] = base[(5 + c2) * 4096];
            mx = fmaxf(mx, logits[c2]);
        }
        float s = 0.0f;
#pragma unroll
        for (int c2 = 0; c2 < NCLS; ++c2) s += __expf(logits[c2] - mx);
        loss += mx + __logf(s) - logits[tcls];
    }

    float dx = sigx - tx, dy = sigy - ty, dw = wo - tw, dh = ho - th;
    loss += 0.5f * (dx * dx + dy * dy + dw * dw + dh * dh);  // coord, cm==1
    float dc = conf - tconf;
    loss += 0.5f * conf_mask * dc * dc;                       // conf

    // ---- block reduction -> deterministic partial ----
#pragma unroll
    for (int off = 32; off > 0; off >>= 1) loss += __shfl_down(loss, off, 64);
    __shared__ float wsum[4];
    if ((threadIdx.x & 63) == 0) wsum[threadIdx.x >> 6] = loss;
    __syncthreads();
    if (threadIdx.x == 0) part[blockIdx.x] = wsum[0] + wsum[1] + wsum[2] + wsum[3];
}

__global__ __launch_bounds__(256) void reduce_kernel(const float* __restrict__ part,
                                                     float* __restrict__ out) {
    float s = 0.0f;
    for (int idx = threadIdx.x; idx < NBLOCKS; idx += 256) s += part[idx];
#pragma unroll
    for (int off = 32; off > 0; off >>= 1) s += __shfl_down(s, off, 64);
    __shared__ float wsum[4];
    if ((threadIdx.x & 63) == 0) wsum[threadIdx.x >> 6] = s;
    __syncthreads();
    if (threadIdx.x == 0) out[0] = wsum[0] + wsum[1] + wsum[2] + wsum[3];
}

extern "C" void kernel_launch(void* const* d_in, const int* in_sizes, int n_in,
                              void* d_out, int out_size, void* d_ws, size_t ws_size,
                              hipStream_t stream) {
    const float* output  = (const float*)d_in[0];
    const float* target  = (const float*)d_in[1];
    const float* anchors = (const float*)d_in[2];
    float* part = (float*)d_ws;   // NBLOCKS floats

    region_loss_kernel<<<NBLOCKS, 256, 0, stream>>>(output, target, anchors, part);
    reduce_kernel<<<1, 256, 0, stream>>>(part, (float*)d_out);
}